// Round 4
// baseline (351.666 us; speedup 1.0000x reference)
//
#include <hip/hip_runtime.h>
#include <hip/hip_bf16.h>

#define HEADS 12
#define HD 64
#define DIM 768
#define SEQ 1024
#define NTOK 8192      // B*N
#define TRIPLE 2304    // 3*DIM
#define BHTOT 96       // B*HEADS

typedef __attribute__((ext_vector_type(8))) short bf16x8;
typedef __attribute__((ext_vector_type(4))) float f32x4;

#define MFMA_B16(a, b, c) __builtin_amdgcn_mfma_f32_16x16x32_bf16((a), (b), (c), 0, 0, 0)

__device__ __forceinline__ unsigned short f2bf(float f) {
  unsigned int u = __float_as_uint(f);
  unsigned int r = (u + 0x7fffu + ((u >> 16) & 1u)) >> 16;
  return (unsigned short)r;
}
__device__ __forceinline__ float qclamp(float v, float lo, float hi) {
  return fminf(fmaxf(v, lo), hi);
}

// ---------------- scalar prep ----------------
__device__ float block_mean(const float* p, int n, int rnd, float* red) {
  int t = threadIdx.x;
  float s = 0.f;
  for (int i = t; i < n; i += 256) { float v = p[i]; s += rnd ? rintf(v) : v; }
  red[t] = s;
  __syncthreads();
  for (int o = 128; o > 0; o >>= 1) { if (t < o) red[t] += red[t + o]; __syncthreads(); }
  float m = red[0] / (float)n;
  __syncthreads();
  return m;
}

__global__ __launch_bounds__(256) void k_prep(
    const float* qaa, const float* qzp, const float* qa, const float* qz,
    const float* ka, const float* kz, const float* va, const float* vz,
    const float* ata, const float* atz, const float* pa, const float* pz,
    float* sc) {
  __shared__ float red[256];
  float r0 = block_mean(qaa, 768, 0, red);
  float r1 = block_mean(qzp, 768, 1, red);
  float r2 = block_mean(qa, 12, 0, red);
  float r3 = block_mean(qz, 12, 1, red);
  float r4 = block_mean(ka, 12, 0, red);
  float r5 = block_mean(kz, 12, 1, red);
  float r6 = block_mean(va, 12, 0, red);
  float r7 = block_mean(vz, 12, 1, red);
  float r8 = block_mean(ata, 12, 0, red);
  float r9 = block_mean(atz, 12, 1, red);
  float r10 = block_mean(pa, 768, 0, red);
  float r11 = block_mean(pz, 768, 1, red);
  if (threadIdx.x == 0) {
    sc[0] = r0; sc[1] = r1; sc[2] = r2; sc[3] = r3; sc[4] = r4; sc[5] = r5;
    sc[6] = r6; sc[7] = r7; sc[8] = r8; sc[9] = r9; sc[10] = r10; sc[11] = r11;
  }
}

// ---------------- activation quantize ----------------
__global__ __launch_bounds__(256) void k_quant_act(
    const float* __restrict__ x, unsigned short* __restrict__ xq,
    const float* __restrict__ sc, int n) {
  int i = (blockIdx.x * 256 + threadIdx.x) * 4;
  if (i >= n) return;
  float a = sc[0], z = sc[1];
  float4 v = *(const float4*)(x + i);
  ushort4 o;
  o.x = f2bf(rintf(qclamp(v.x / a + z, -8.f, 7.f)) - z);
  o.y = f2bf(rintf(qclamp(v.y / a + z, -8.f, 7.f)) - z);
  o.z = f2bf(rintf(qclamp(v.z / a + z, -8.f, 7.f)) - z);
  o.w = f2bf(rintf(qclamp(v.w / a + z, -8.f, 7.f)) - z);
  *(ushort4*)(xq + i) = o;
}

// ---------------- weight quantize ----------------
__global__ __launch_bounds__(256) void k_quant_w(
    const float* __restrict__ w, const float* __restrict__ alpha,
    unsigned short* __restrict__ wq, int n, int K) {
  int i = (blockIdx.x * 256 + threadIdx.x) * 4;
  if (i >= n) return;
  float a = alpha[i / K];
  float4 v = *(const float4*)(w + i);
  ushort4 o;
  o.x = f2bf(rintf(qclamp(v.x / a, -8.f, 7.f)));
  o.y = f2bf(rintf(qclamp(v.y / a, -8.f, 7.f)));
  o.z = f2bf(rintf(qclamp(v.z / a, -8.f, 7.f)));
  o.w = f2bf(rintf(qclamp(v.w / a, -8.f, 7.f)));
  *(ushort4*)(wq + i) = o;
}

// ---------------- qkv GEMM with fused LN+quant epilogue ----------------
// 128x128 tile, BK=64, 4 waves (64x64 quadrant each). Each wave's 64-col range
// is exactly one head's d-range -> per-row LN via shfl_xor over the 16 lr lanes.
__global__ __launch_bounds__(256) void k_gemm_qkv(
    const unsigned short* __restrict__ A, const unsigned short* __restrict__ Bw,
    const float* __restrict__ colscale, const float* __restrict__ sc,
    const float* __restrict__ nqg, const float* __restrict__ nqb,
    const float* __restrict__ nkg, const float* __restrict__ nkb,
    unsigned short* __restrict__ q2b, unsigned short* __restrict__ k2b,
    unsigned short* __restrict__ v2t) {
  __shared__ unsigned short As[128][72];
  __shared__ unsigned short Bs[128][72];
  const int t = threadIdx.x;
  const int brow = blockIdx.x * 128, bcol = blockIdx.y * 128;
  const int w = t >> 6, l = t & 63;
  const int lr = l & 15, lg = l >> 4;
  const int wr = (w >> 1) * 64, wc = (w & 1) * 64;
  const int sr = t >> 1, sc0 = (t & 1) * 32;
  f32x4 acc[4][4] = {};
  for (int kt = 0; kt < DIM; kt += 64) {
    const uint4* ga = (const uint4*)(A + (size_t)(brow + sr) * DIM + kt + sc0);
    uint4 a0 = ga[0], a1 = ga[1], a2 = ga[2], a3 = ga[3];
    const uint4* gb = (const uint4*)(Bw + (size_t)(bcol + sr) * DIM + kt + sc0);
    uint4 b0 = gb[0], b1 = gb[1], b2 = gb[2], b3 = gb[3];
    __syncthreads();
    { uint4* d = (uint4*)&As[sr][sc0]; d[0] = a0; d[1] = a1; d[2] = a2; d[3] = a3; }
    { uint4* d = (uint4*)&Bs[sr][sc0]; d[0] = b0; d[1] = b1; d[2] = b2; d[3] = b3; }
    __syncthreads();
#pragma unroll
    for (int ks = 0; ks < 2; ++ks) {
      bf16x8 af[4], bfr[4];
#pragma unroll
      for (int i = 0; i < 4; ++i) {
        af[i] = *(const bf16x8*)&As[wr + i * 16 + lr][ks * 32 + lg * 8];
        bfr[i] = *(const bf16x8*)&Bs[wc + i * 16 + lr][ks * 32 + lg * 8];
      }
#pragma unroll
      for (int i = 0; i < 4; ++i)
#pragma unroll
        for (int j = 0; j < 4; ++j)
          acc[i][j] = MFMA_B16(af[i], bfr[j], acc[i][j]);
    }
  }
  // ---- epilogue: scale, then per-segment LN/quant ----
  const float sact = sc[0];
  float s_j[4];
#pragma unroll
  for (int j = 0; j < 4; ++j) s_j[j] = sact * colscale[bcol + wc + j * 16 + lr];
#pragma unroll
  for (int i = 0; i < 4; ++i)
#pragma unroll
    for (int j = 0; j < 4; ++j)
#pragma unroll
      for (int r = 0; r < 4; ++r) acc[i][j][r] *= s_j[j];

  const int seg = bcol / DIM;                 // 0=q,1=k,2=v
  const int h_ = ((bcol % DIM) + wc) / 64;    // head for this wave
  if (seg < 2) {
    const float* gp = seg ? nkg : nqg;
    const float* bp = seg ? nkb : nqb;
    const float aq_ = seg ? sc[4] : sc[2];
    const float zq_ = seg ? sc[5] : sc[3];
    float gj[4], bj[4];
#pragma unroll
    for (int j = 0; j < 4; ++j) { gj[j] = gp[j * 16 + lr]; bj[j] = bp[j * 16 + lr]; }
    unsigned short* dstb = seg ? k2b : q2b;
#pragma unroll
    for (int i = 0; i < 4; ++i)
#pragma unroll
      for (int r = 0; r < 4; ++r) {
        float sum = acc[i][0][r] + acc[i][1][r] + acc[i][2][r] + acc[i][3][r];
        sum += __shfl_xor(sum, 1); sum += __shfl_xor(sum, 2);
        sum += __shfl_xor(sum, 4); sum += __shfl_xor(sum, 8);
        float m = sum * (1.0f / 64.0f);
        float vs = 0.f;
#pragma unroll
        for (int j = 0; j < 4; ++j) { float d = acc[i][j][r] - m; vs += d * d; }
        vs += __shfl_xor(vs, 1); vs += __shfl_xor(vs, 2);
        vs += __shfl_xor(vs, 4); vs += __shfl_xor(vs, 8);
        float inv = 1.0f / sqrtf(vs * (1.0f / 64.0f) + 1e-5f);
        int row = brow + wr + i * 16 + lg * 4 + r;
        int b_ = row >> 10, n_ = row & (SEQ - 1);
        unsigned short* dst = dstb + (((size_t)(b_ * HEADS + h_) << 10) + n_) * HD;
#pragma unroll
        for (int j = 0; j < 4; ++j) {
          float yv = (acc[i][j][r] - m) * inv * gj[j] + bj[j];
          float qv = rintf(qclamp(yv / aq_ + zq_, -8.f, 7.f)) - zq_;
          dst[j * 16 + lr] = f2bf(qv);
        }
      }
  } else {
    const float av_ = sc[6], zv = sc[7];
#pragma unroll
    for (int i = 0; i < 4; ++i)
#pragma unroll
      for (int r = 0; r < 4; ++r) {
        int row = brow + wr + i * 16 + lg * 4 + r;
        int b_ = row >> 10, n_ = row & (SEQ - 1);
        unsigned short* dst = v2t + ((size_t)(b_ * HEADS + h_) << 16) + n_;
#pragma unroll
        for (int j = 0; j < 4; ++j) {
          float qv = rintf(qclamp(acc[i][j][r] / av_ + zv, -8.f, 7.f)) - zv;
          dst[(size_t)(j * 16 + lr) * SEQ] = f2bf(qv);
        }
      }
  }
}

// ---------------- proj GEMM (f32 out + bias) ----------------
__global__ __launch_bounds__(256) void k_gemm(
    const unsigned short* __restrict__ A, const unsigned short* __restrict__ Bw,
    float* __restrict__ out, const float* __restrict__ colscale,
    const float* __restrict__ bias, const float* __restrict__ sc, int sact_idx,
    int M, int Nt, int K) {
  __shared__ unsigned short As[128][72];
  __shared__ unsigned short Bs[128][72];
  const int t = threadIdx.x;
  const int brow = blockIdx.x * 128, bcol = blockIdx.y * 128;
  const int w = t >> 6, l = t & 63;
  const int lr = l & 15, lg = l >> 4;
  const int wr = (w >> 1) * 64, wc = (w & 1) * 64;
  const int sr = t >> 1, sc0 = (t & 1) * 32;
  f32x4 acc[4][4] = {};
  for (int kt = 0; kt < K; kt += 64) {
    const uint4* ga = (const uint4*)(A + (size_t)(brow + sr) * K + kt + sc0);
    uint4 a0 = ga[0], a1 = ga[1], a2 = ga[2], a3 = ga[3];
    const uint4* gb = (const uint4*)(Bw + (size_t)(bcol + sr) * K + kt + sc0);
    uint4 b0 = gb[0], b1 = gb[1], b2 = gb[2], b3 = gb[3];
    __syncthreads();
    { uint4* d = (uint4*)&As[sr][sc0]; d[0] = a0; d[1] = a1; d[2] = a2; d[3] = a3; }
    { uint4* d = (uint4*)&Bs[sr][sc0]; d[0] = b0; d[1] = b1; d[2] = b2; d[3] = b3; }
    __syncthreads();
#pragma unroll
    for (int ks = 0; ks < 2; ++ks) {
      bf16x8 af[4], bfr[4];
#pragma unroll
      for (int i = 0; i < 4; ++i) {
        af[i] = *(const bf16x8*)&As[wr + i * 16 + lr][ks * 32 + lg * 8];
        bfr[i] = *(const bf16x8*)&Bs[wc + i * 16 + lr][ks * 32 + lg * 8];
      }
#pragma unroll
      for (int i = 0; i < 4; ++i)
#pragma unroll
        for (int j = 0; j < 4; ++j)
          acc[i][j] = MFMA_B16(af[i], bfr[j], acc[i][j]);
    }
  }
  const float sact = sc[sact_idx];
#pragma unroll
  for (int j = 0; j < 4; ++j) {
    const int col = bcol + wc + j * 16 + lr;
    const float s = sact * colscale[col];
    const float bb = bias ? bias[col] : 0.f;
#pragma unroll
    for (int i = 0; i < 4; ++i) {
      const int row0 = brow + wr + i * 16 + lg * 4;
#pragma unroll
      for (int r = 0; r < 4; ++r)
        out[(size_t)(row0 + r) * Nt + col] = acc[i][j][r] * s + bb;
    }
  }
}

// ---------------- fused attention, barrier-free ----------------
// 4 waves x 32 q-rows; K/V streamed from L2 (128KB/head, resident); only
// per-wave Ps in LDS. No max-subtraction: |S| <= 4096*aq*ak/8 <= ~1.3.
__global__ __launch_bounds__(256, 4) void k_attn(
    const unsigned short* __restrict__ q2b, const unsigned short* __restrict__ k2b,
    const unsigned short* __restrict__ v2t, unsigned short* __restrict__ x1q,
    const float* __restrict__ sc) {
  __shared__ unsigned short Ps[4][32][136];  // per-wave quantized P (128-k window)
  const int t = threadIdx.x;
  const int w = t >> 6, l = t & 63;
  const int lr = l & 15, lg = l >> 4;
  // XCD-bijective swizzle: 768 blocks = 8 * 96 -> all 8 q-chunks of a head on one XCD
  const int bid = (int)(blockIdx.x & 7) * 96 + (int)(blockIdx.x >> 3);
  const int bh = bid >> 3, qc = bid & 7;
  const unsigned short* Qg = q2b + (size_t)bh * (SEQ * HD);
  const unsigned short* Kg = k2b + (size_t)bh * (SEQ * HD);
  const unsigned short* Vg = v2t + (size_t)bh * (SEQ * HD);
  const float aq = sc[2], ak = sc[4], av_ = sc[6], aa = sc[8], za = sc[9];
  const float ap = sc[10], zpp = sc[11];
  const float sqk2 = aq * ak * 0.125f * 1.44269504f;  // fold log2(e) into scale
  const float spv = aa * av_;
  const int qr0 = qc * 128 + w * 32;

  bf16x8 qf[2][2];
#pragma unroll
  for (int rt = 0; rt < 2; ++rt)
#pragma unroll
    for (int ks = 0; ks < 2; ++ks)
      qf[rt][ks] = *(const bf16x8*)(Qg + (size_t)(qr0 + rt * 16 + lr) * HD + ks * 32 + lg * 8);

  // ---- pass 1: denominator only (no max needed; S bounded)
  float lacc[2][4] = {};
#pragma unroll 4
  for (int c = 0; c < 64; ++c) {
    const unsigned short* kr = Kg + (size_t)(c * 16 + lr) * HD + lg * 8;
    bf16x8 kf0 = *(const bf16x8*)kr;
    bf16x8 kf1 = *(const bf16x8*)(kr + 32);
#pragma unroll
    for (int rt = 0; rt < 2; ++rt) {
      f32x4 s4 = {0.f, 0.f, 0.f, 0.f};
      s4 = MFMA_B16(qf[rt][0], kf0, s4);
      s4 = MFMA_B16(qf[rt][1], kf1, s4);
#pragma unroll
      for (int r = 0; r < 4; ++r)
        lacc[rt][r] += __builtin_amdgcn_exp2f(s4[r] * sqk2);
    }
  }
  // reduce l across the 16 lr lanes (each holds k = lr mod 16 partials)
#pragma unroll
  for (int off = 1; off < 16; off <<= 1)
#pragma unroll
    for (int rt = 0; rt < 2; ++rt)
#pragma unroll
      for (int r = 0; r < 4; ++r) lacc[rt][r] += __shfl_xor(lacc[rt][r], off);
  float pinv[2][4];
#pragma unroll
  for (int rt = 0; rt < 2; ++rt)
#pragma unroll
    for (int r = 0; r < 4; ++r) pinv[rt][r] = 1.0f / (lacc[rt][r] * aa);

  // ---- pass 2: recompute S, quantize P -> per-wave LDS, PV (no barriers)
  f32x4 oacc[2][4] = {};
  for (int kt = 0; kt < SEQ; kt += 128) {
#pragma unroll
    for (int ct = 0; ct < 8; ++ct) {
      const unsigned short* kr = Kg + (size_t)(kt + ct * 16 + lr) * HD + lg * 8;
      bf16x8 kf0 = *(const bf16x8*)kr;
      bf16x8 kf1 = *(const bf16x8*)(kr + 32);
#pragma unroll
      for (int rt = 0; rt < 2; ++rt) {
        f32x4 s4 = {0.f, 0.f, 0.f, 0.f};
        s4 = MFMA_B16(qf[rt][0], kf0, s4);
        s4 = MFMA_B16(qf[rt][1], kf1, s4);
#pragma unroll
        for (int r = 0; r < 4; ++r) {
          float e = __builtin_amdgcn_exp2f(s4[r] * sqk2);
          float p = fmaf(e, pinv[rt][r], za);
          float qv = rintf(qclamp(p, 0.f, 15.f)) - za;
          Ps[w][rt * 16 + lg * 4 + r][ct * 16 + lr] = f2bf(qv);
        }
      }
    }
#pragma unroll
    for (int ks2 = 0; ks2 < 4; ++ks2) {
      bf16x8 vf[4], pf[2];
#pragma unroll
      for (int dt = 0; dt < 4; ++dt)
        vf[dt] = *(const bf16x8*)(Vg + (size_t)(dt * 16 + lr) * SEQ + kt + ks2 * 32 + lg * 8);
#pragma unroll
      for (int rt = 0; rt < 2; ++rt)
        pf[rt] = *(const bf16x8*)&Ps[w][rt * 16 + lr][ks2 * 32 + lg * 8];
#pragma unroll
      for (int rt = 0; rt < 2; ++rt)
#pragma unroll
        for (int dt = 0; dt < 4; ++dt)
          oacc[rt][dt] = MFMA_B16(pf[rt], vf[dt], oacc[rt][dt]);
    }
  }
  // ---- epilogue: x1 = spv*acc, fused proj-input quantization
  const int b_ = bh / HEADS, h_ = bh % HEADS;
#pragma unroll
  for (int rt = 0; rt < 2; ++rt)
#pragma unroll
    for (int dt = 0; dt < 4; ++dt) {
      const int col = h_ * HD + dt * 16 + lr;
#pragma unroll
      for (int r = 0; r < 4; ++r) {
        const int qrow = qr0 + rt * 16 + lg * 4 + r;
        float x1v = oacc[rt][dt][r] * spv;
        float xv = rintf(qclamp(x1v / ap + zpp, -8.f, 7.f)) - zpp;
        x1q[(size_t)(b_ * SEQ + qrow) * DIM + col] = f2bf(xv);
      }
    }
}

extern "C" void kernel_launch(void* const* d_in, const int* in_sizes, int n_in,
                              void* d_out, int out_size, void* d_ws, size_t ws_size,
                              hipStream_t stream) {
  const float* x0      = (const float*)d_in[0];
  const float* qkvw    = (const float*)d_in[1];
  const float* qkv_aw  = (const float*)d_in[2];
  const float* qkv_aa  = (const float*)d_in[3];
  const float* qkv_azp = (const float*)d_in[4];
  const float* nqg     = (const float*)d_in[5];
  const float* nqb     = (const float*)d_in[6];
  const float* nkg     = (const float*)d_in[7];
  const float* nkb     = (const float*)d_in[8];
  const float* q_a     = (const float*)d_in[9];
  const float* q_z     = (const float*)d_in[10];
  const float* k_a     = (const float*)d_in[11];
  const float* k_z     = (const float*)d_in[12];
  const float* v_a     = (const float*)d_in[13];
  const float* v_z     = (const float*)d_in[14];
  const float* at_a    = (const float*)d_in[15];
  const float* at_z    = (const float*)d_in[16];
  const float* pw      = (const float*)d_in[17];
  const float* pb      = (const float*)d_in[18];
  const float* p_aw    = (const float*)d_in[19];
  const float* p_aa    = (const float*)d_in[20];
  const float* p_azp   = (const float*)d_in[21];
  float* out = (float*)d_out;

  char* ws = (char*)d_ws;
  size_t off = 0;
  float* scal = (float*)(ws); off = 256;
  unsigned short* x0q  = (unsigned short*)(ws + off); off += (size_t)NTOK * DIM * 2;
  unsigned short* qwq  = (unsigned short*)(ws + off); off += (size_t)TRIPLE * DIM * 2;
  unsigned short* pwq  = (unsigned short*)(ws + off); off += (size_t)DIM * DIM * 2;
  unsigned short* q2b  = (unsigned short*)(ws + off); off += (size_t)BHTOT * SEQ * HD * 2;
  unsigned short* k2b  = (unsigned short*)(ws + off); off += (size_t)BHTOT * SEQ * HD * 2;
  unsigned short* v2t  = (unsigned short*)(ws + off); off += (size_t)BHTOT * SEQ * HD * 2;
  unsigned short* x1q  = (unsigned short*)(ws + off); off += (size_t)NTOK * DIM * 2;

  k_prep<<<1, 256, 0, stream>>>(qkv_aa, qkv_azp, q_a, q_z, k_a, k_z, v_a, v_z,
                                at_a, at_z, p_aa, p_azp, scal);
  k_quant_act<<<(NTOK * DIM) / 1024, 256, 0, stream>>>(x0, x0q, scal, NTOK * DIM);
  k_quant_w<<<(TRIPLE * DIM) / 1024, 256, 0, stream>>>(qkvw, qkv_aw, qwq, TRIPLE * DIM, DIM);
  k_quant_w<<<(DIM * DIM) / 1024, 256, 0, stream>>>(pw, p_aw, pwq, DIM * DIM, DIM);
  k_gemm_qkv<<<dim3(NTOK / 128, TRIPLE / 128), 256, 0, stream>>>(
      x0q, qwq, qkv_aw, scal, nqg, nqb, nkg, nkb, q2b, k2b, v2t);
  k_attn<<<BHTOT * 8, 256, 0, stream>>>(q2b, k2b, v2t, x1q, scal);
  k_gemm<<<dim3(NTOK / 128, DIM / 128), 256, 0, stream>>>(
      x1q, pwq, out, p_aw, pb, scal, 10, NTOK, DIM, DIM);
}